// Round 5
// baseline (128.517 us; speedup 1.0000x reference)
//
#include <hip/hip_runtime.h>

typedef float  f32x4  __attribute__((ext_vector_type(4)));
typedef short  bf16x8 __attribute__((ext_vector_type(8)));

#define HWI    16384          // 128*128
#define IMG    (96*16384)     // per-batch elements
#define NPIX   50331648       // 32*96*128*128

// ws layout (float offsets)
#define WS_G   0              // 9216 floats
#define WS_SP  16384          // 512 blocks * 8 partial floats = 4096

__device__ __forceinline__ unsigned short f2bf(float f){
    unsigned u = __builtin_bit_cast(unsigned, f);
    u += 0x7fffu + ((u >> 16) & 1u);          // round-to-nearest-even
    return (unsigned short)(u >> 16);
}

// ---------------- kernel 0: G = convq^T @ convk (96x96) ----------------
__global__ void kG(const float* __restrict__ cq, const float* __restrict__ ck,
                   float* __restrict__ G){
    int idx = blockIdx.x * 256 + threadIdx.x;
    if (idx >= 9216) return;
    int c = idx / 96, cp = idx - c * 96;
    float s = 0.f;
    #pragma unroll 8
    for (int o = 0; o < 96; ++o) s += cq[o*96 + c] * ck[o*96 + cp];
    G[idx] = s;
}

// ---------------- kernel 1: fused Gram (MFMA) + <G,M> dot -> partials ----------------
// Round-0 structure + T3/T4-style pipelining: raw s_barrier with ONLY
// lgkmcnt(0) (no vmcnt drain), so global loads stay in flight ACROSS the
// barrier. Two register sets (v0 = even steps, v1 = odd steps, statically
// indexed) give each load ~1.5 steps of latency cover instead of ~0.3.
__launch_bounds__(384, 3)
__global__ void kM(const float* __restrict__ x, const float* __restrict__ G,
                   float* __restrict__ sp){
    const int blk = blockIdx.x;
    const int b = blk >> 4, wp = (blk >> 3) & 1, ks = blk & 7;
    const int tid = threadIdx.x;
    const int wave = tid >> 6, lane = tid & 63;
    const int q  = wave >> 1;                  // 0 tt, 1 tb, 2 bb
    const int h  = wave & 1;                   // row-half of quadrant
    const int qr = (q == 2) ? 1 : 0;
    const int qc = (q == 0) ? 0 : 1;

    __shared__ unsigned short Zs[2][192][40];  // double buffer, 32 valid k + pad

    f32x4 acc[3][6];
    #pragma unroll
    for (int a = 0; a < 3; ++a)
      #pragma unroll
      for (int b2 = 0; b2 < 6; ++b2)
        acc[a][b2] = (f32x4){0.f, 0.f, 0.f, 0.f};

    const int l16 = tid & 15, rr = tid >> 4;   // rr in [0,24)
    const float* xb = x + (size_t)b * IMG + wp * 64 + l16 * 4;
    const int frow = lane & 15, fko = (lane >> 4) << 3;
    const int i0 = ks * 8;

    // waitcnt + barrier fused in ONE asm-with-memory-clobber: no LDS/global
    // op can be moved across it by any compiler stage, and vmcnt is NOT
    // drained (unlike __syncthreads) -> prefetch loads survive the barrier.
    #define BARRIER_LGKM() asm volatile("s_waitcnt lgkmcnt(0)\ns_barrier" ::: "memory")

    #define LOADR(dst, ii) do { \
        _Pragma("unroll") \
        for (int p = 0; p < 8; ++p){ \
            const int row_ = rr + p * 24; \
            const int cch_ = (row_ < 96) ? row_ : row_ - 96; \
            const int hh_  = (row_ < 96) ? (ii) : (ii) + 64; \
            dst[p] = *(const f32x4*)(xb + (size_t)cch_ * HWI + hh_ * 128); \
        } } while(0)

    #define PACK(src, bufc) do { \
        _Pragma("unroll") \
        for (int p = 0; p < 8; ++p){ \
            const int row_ = rr + p * 24; \
            unsigned pk_ = (wp == 0) \
                ? ((unsigned)f2bf(src[p][0]) | ((unsigned)f2bf(src[p][2]) << 16)) \
                : ((unsigned)f2bf(src[p][1]) | ((unsigned)f2bf(src[p][3]) << 16)); \
            *(unsigned*)(&Zs[bufc][row_][l16 * 2]) = pk_; \
        } } while(0)

    #define FRAG_MFMA(bufc) do { \
        bf16x8 af[3], bfv[6]; \
        _Pragma("unroll") \
        for (int t3 = 0; t3 < 3; ++t3) \
            af[t3] = *(const bf16x8*)(&Zs[bufc][qr*96 + (h*3 + t3)*16 + frow][fko]); \
        _Pragma("unroll") \
        for (int t6 = 0; t6 < 6; ++t6) \
            bfv[t6] = *(const bf16x8*)(&Zs[bufc][qc*96 + t6*16 + frow][fko]); \
        _Pragma("unroll") \
        for (int tr = 0; tr < 3; ++tr) \
          _Pragma("unroll") \
          for (int tc = 0; tc < 6; ++tc) \
            acc[tr][tc] = __builtin_amdgcn_mfma_f32_16x16x32_bf16( \
                              af[tr], bfv[tc], acc[tr][tc], 0, 0, 0); \
        } while(0)

    f32x4 v0[8], v1[8];
    LOADR(v0, i0 + 0);                         // step 0 (even set)
    LOADR(v1, i0 + 1);                         // step 1 (odd set)

    #pragma unroll 1
    for (int it = 0; it < 4; ++it){
        const int s0 = it * 2;                 // even step: 0,2,4,6
        // ---- even phase: consume v0 / buffer 0
        PACK(v0, 0);                           // compiler emits precise vmcnt(8)
        BARRIER_LGKM();
        if (s0 < 6) LOADR(v0, i0 + s0 + 2);    // in flight across next barrier
        FRAG_MFMA(0);
        // ---- odd phase: consume v1 / buffer 1
        PACK(v1, 1);
        BARRIER_LGKM();
        if (s0 < 5) LOADR(v1, i0 + s0 + 3);
        FRAG_MFMA(1);
    }

    #undef BARRIER_LGKM
    #undef LOADR
    #undef PACK
    #undef FRAG_MFMA

    // fused dot with G (and G^T for the tb quadrant)
    const int r0 = (lane >> 4) * 4, c0 = lane & 15;
    float p0 = 0.f, p1 = 0.f;
    #pragma unroll
    for (int tr = 0; tr < 3; ++tr){
      #pragma unroll
      for (int tc = 0; tc < 6; ++tc){
        #pragma unroll
        for (int e = 0; e < 4; ++e){
          const int R = (h*3 + tr)*16 + r0 + e;
          const int C = tc*16 + c0;
          const float m = acc[tr][tc][e];
          p0 += G[R*96 + C] * m;
          if (q == 1) p1 += G[C*96 + R] * m;
        }
      }
    }
    #pragma unroll
    for (int off = 32; off > 0; off >>= 1){
        p0 += __shfl_down(p0, off, 64);
        if (q == 1) p1 += __shfl_down(p1, off, 64);
    }
    if (lane == 0){
        float* s = sp + (size_t)blk * 8;
        s[wave] = p0;                          // slots 0..5
        if (q == 1) s[6 + h] = p1;             // slots 6..7 (bt)
    }
}

// ---------------- kernel 2: output mix + attn recompute + logdet ----------------
__launch_bounds__(256)
__global__ void kOut(const float* __restrict__ x, const float* __restrict__ sp,
                     const float* __restrict__ o1p, const float* __restrict__ o2p,
                     const float* __restrict__ o3p, float* __restrict__ out){
    __shared__ float A[2][4];                  // [wp][a00,a01,a10,a11]
    const int blk = blockIdx.x, tid = threadIdx.x;
    const int r = blk >> 3;                    // b*96 + c
    const int b = r / 96;

    if (tid < 8){
        const int wp = tid >> 2, comp = tid & 3;
        const int s0 = (comp == 0) ? 0 : (comp == 1) ? 2 : (comp == 2) ? 6 : 4;
        const float* base = sp + (size_t)((b*2 + wp) * 8) * 8;
        float s = 0.f;
        #pragma unroll
        for (int ks = 0; ks < 8; ++ks) s += base[ks*8 + s0] + base[ks*8 + s0 + 1];
        s += o2p[0];
        s = (s >= 0.f ? s : 1e-4f * s) + o3p[0];
        if (comp == 0 || comp == 3) s += o1p[0];
        A[wp][comp] = s;
    }
    __syncthreads();

    if (tid == 8 && (blk % 768) == 0){
        float ld = logf(fabsf(A[0][0]*A[0][3] - A[0][1]*A[0][2]))
                 + logf(fabsf(A[1][0]*A[1][3] - A[1][1]*A[1][2]));
        out[NPIX + b] = ld * 196608.0f;        // p*(p/2)*C = 64*32*96
    }

    const int idx = blk * 256 + tid;
    const int wq = idx & 31;
    const int i  = (idx >> 5) & 63;
    const size_t base = ((size_t)r * 128 + i) * 128 + wq * 4;
    f32x4 top = *(const f32x4*)(x + base);
    f32x4 bot = *(const f32x4*)(x + base + 8192);
    const int wp = wq >> 4;
    const float a00 = A[wp][0], a01 = A[wp][1], a10 = A[wp][2], a11 = A[wp][3];
    f32x4 ot, ob;
    #pragma unroll
    for (int e = 0; e < 4; ++e){
        const bool mix = ((wp + e) & 1) != 0;
        ot[e] = mix ? (a00 * top[e] + a01 * bot[e]) : top[e];
        ob[e] = mix ? (a10 * top[e] + a11 * bot[e]) : bot[e];
    }
    __builtin_nontemporal_store(ot, (f32x4*)(out + base));
    __builtin_nontemporal_store(ob, (f32x4*)(out + base + 8192));
}

extern "C" void kernel_launch(void* const* d_in, const int* in_sizes, int n_in,
                              void* d_out, int out_size, void* d_ws, size_t ws_size,
                              hipStream_t stream){
    const float* x  = (const float*)d_in[0];
    const float* cq = (const float*)d_in[1];
    const float* ck = (const float*)d_in[2];
    const float* o1 = (const float*)d_in[3];
    const float* o2 = (const float*)d_in[4];
    const float* o3 = (const float*)d_in[5];
    float* out = (float*)d_out;
    float* ws  = (float*)d_ws;

    kG  <<<36, 256, 0, stream>>>(cq, ck, ws + WS_G);
    kM  <<<512, 384, 0, stream>>>(x, ws + WS_G, ws + WS_SP);
    kOut<<<24576, 256, 0, stream>>>(x, ws + WS_SP, o1, o2, o3, out);
}

// Round 6
// 106.698 us; speedup vs baseline: 1.2045x; 1.2045x over previous
//
#include <hip/hip_runtime.h>

typedef float  f32x4  __attribute__((ext_vector_type(4)));
typedef short  bf16x8 __attribute__((ext_vector_type(8)));

#define HWI    16384          // 128*128
#define IMG    (96*16384)     // per-batch elements
#define NPIX   50331648       // 32*96*128*128

// ws layout (float offsets)
#define WS_G   0              // 9216 floats
#define WS_SP  16384          // 512 blocks * 8 partial floats = 4096

// ---------------- kernel 0: G = convq^T @ convk (96x96) ----------------
__global__ void kG(const float* __restrict__ cq, const float* __restrict__ ck,
                   float* __restrict__ G){
    int idx = blockIdx.x * 256 + threadIdx.x;
    if (idx >= 9216) return;
    int c = idx / 96, cp = idx - c * 96;
    float s = 0.f;
    #pragma unroll 8
    for (int o = 0; o < 96; ++o) s += cq[o*96 + c] * ck[o*96 + cp];
    G[idx] = s;
}

// ---------------- kernel 1: fused Gram (MFMA) + <G,M> dot -> partials ----------------
// 1D grid of 512: blk = (b*2+wp)*8 + ks. block 384 (6 waves).
// waves 0,1 -> tt; 2,3 -> tb (also bt via G^T); 4,5 -> bb. Each wave:
// 48x96 half-quadrant (3x6 MFMA tiles), dot with G in regs, wave-reduce,
// write its scalar(s) to sp[blk*8 + slot]  (slots 0..5 = p0, 6..7 = p1).
// Double-buffered LDS, ONE barrier per step, 8-row register prefetch so
// next step's global loads are in flight across the MFMA phase.
// Pack uses v_cvt_pk_bf16_f32 (1 VALU op / 2 floats, RNE) instead of the
// 4-5-op manual bit sequence: pure instruction-count reduction on the
// pack critical path (compiler cannot derive cvt_pk from integer bit-ops).
__launch_bounds__(384, 3)
__global__ void kM(const float* __restrict__ x, const float* __restrict__ G,
                   float* __restrict__ sp){
    const int blk = blockIdx.x;
    const int b = blk >> 4, wp = (blk >> 3) & 1, ks = blk & 7;
    const int tid = threadIdx.x;
    const int wave = tid >> 6, lane = tid & 63;
    const int q  = wave >> 1;                  // 0 tt, 1 tb, 2 bb
    const int h  = wave & 1;                   // row-half of quadrant
    const int qr = (q == 2) ? 1 : 0;
    const int qc = (q == 0) ? 0 : 1;

    __shared__ unsigned short Zs[2][192][40];  // double buffer, 32 valid k + pad

    f32x4 acc[3][6];
    #pragma unroll
    for (int a = 0; a < 3; ++a)
      #pragma unroll
      for (int b2 = 0; b2 < 6; ++b2)
        acc[a][b2] = (f32x4){0.f, 0.f, 0.f, 0.f};

    const int l16 = tid & 15, rr = tid >> 4;   // rr in [0,24)
    const float* xb = x + (size_t)b * IMG + wp * 64 + l16 * 4;
    const int frow = lane & 15, fko = (lane >> 4) << 3;

    f32x4 v[8];
    {   // prologue: load step 0
        const int i0 = ks * 8;
        #pragma unroll
        for (int p = 0; p < 8; ++p){
            const int row = rr + p * 24;
            const int cch = (row < 96) ? row : row - 96;
            const int hh  = (row < 96) ? i0  : i0 + 64;
            v[p] = *(const f32x4*)(xb + (size_t)cch * HWI + hh * 128);
        }
    }

    for (int step = 0; step < 8; ++step){
        const int cur = step & 1;
        // pack prefetched data into current LDS buffer (hw RNE bf16 pack)
        #pragma unroll
        for (int p = 0; p < 8; ++p){
            const int row = rr + p * 24;
            unsigned pk;
            if (wp == 0)                       // block-uniform branch (free)
                asm("v_cvt_pk_bf16_f32 %0, %1, %2"
                    : "=v"(pk) : "v"(v[p][0]), "v"(v[p][2]));
            else
                asm("v_cvt_pk_bf16_f32 %0, %1, %2"
                    : "=v"(pk) : "v"(v[p][1]), "v"(v[p][3]));
            *(unsigned*)(&Zs[cur][row][l16 * 2]) = pk;
        }
        __syncthreads();
        // prefetch next step (in flight across the MFMA phase)
        if (step < 7){
            const int i = ks * 8 + step + 1;
            #pragma unroll
            for (int p = 0; p < 8; ++p){
                const int row = rr + p * 24;
                const int cch = (row < 96) ? row : row - 96;
                const int hh  = (row < 96) ? i   : i + 64;
                v[p] = *(const f32x4*)(xb + (size_t)cch * HWI + hh * 128);
            }
        }
        // fragments + MFMA from current buffer
        bf16x8 af[3], bfv[6];
        #pragma unroll
        for (int t3 = 0; t3 < 3; ++t3)
            af[t3] = *(const bf16x8*)(&Zs[cur][qr*96 + (h*3 + t3)*16 + frow][fko]);
        #pragma unroll
        for (int t6 = 0; t6 < 6; ++t6)
            bfv[t6] = *(const bf16x8*)(&Zs[cur][qc*96 + t6*16 + frow][fko]);
        #pragma unroll
        for (int tr = 0; tr < 3; ++tr)
          #pragma unroll
          for (int tc = 0; tc < 6; ++tc)
            acc[tr][tc] = __builtin_amdgcn_mfma_f32_16x16x32_bf16(
                              af[tr], bfv[tc], acc[tr][tc], 0, 0, 0);
    }

    // fused dot with G (and G^T for the tb quadrant)
    const int r0 = (lane >> 4) * 4, c0 = lane & 15;
    float p0 = 0.f, p1 = 0.f;
    #pragma unroll
    for (int tr = 0; tr < 3; ++tr){
      #pragma unroll
      for (int tc = 0; tc < 6; ++tc){
        #pragma unroll
        for (int e = 0; e < 4; ++e){
          const int R = (h*3 + tr)*16 + r0 + e;
          const int C = tc*16 + c0;
          const float m = acc[tr][tc][e];
          p0 += G[R*96 + C] * m;
          if (q == 1) p1 += G[C*96 + R] * m;
        }
      }
    }
    #pragma unroll
    for (int off = 32; off > 0; off >>= 1){
        p0 += __shfl_down(p0, off, 64);
        if (q == 1) p1 += __shfl_down(p1, off, 64);
    }
    if (lane == 0){
        float* s = sp + (size_t)blk * 8;
        s[wave] = p0;                          // slots 0..5
        if (q == 1) s[6 + h] = p1;             // slots 6..7 (bt)
    }
}

// ---------------- kernel 2: output mix + attn recompute + logdet ----------------
// Each block covers one r=(b*96+c) slice of 2048 floats (256 threads * f32x4
// top/bot pair). Threads 0..7 rebuild the two 2x2 attn matrices for this b
// from the 16 partials; blocks at blk%768==0 also emit logdet for their b.
__launch_bounds__(256)
__global__ void kOut(const float* __restrict__ x, const float* __restrict__ sp,
                     const float* __restrict__ o1p, const float* __restrict__ o2p,
                     const float* __restrict__ o3p, float* __restrict__ out){
    __shared__ float A[2][4];                  // [wp][a00,a01,a10,a11]
    const int blk = blockIdx.x, tid = threadIdx.x;
    const int r = blk >> 3;                    // b*96 + c
    const int b = r / 96;

    if (tid < 8){
        const int wp = tid >> 2, comp = tid & 3;
        const int s0 = (comp == 0) ? 0 : (comp == 1) ? 2 : (comp == 2) ? 6 : 4;
        const float* base = sp + (size_t)((b*2 + wp) * 8) * 8;
        float s = 0.f;
        #pragma unroll
        for (int ks = 0; ks < 8; ++ks) s += base[ks*8 + s0] + base[ks*8 + s0 + 1];
        s += o2p[0];
        s = (s >= 0.f ? s : 1e-4f * s) + o3p[0];
        if (comp == 0 || comp == 3) s += o1p[0];
        A[wp][comp] = s;
    }
    __syncthreads();

    if (tid == 8 && (blk % 768) == 0){
        float ld = logf(fabsf(A[0][0]*A[0][3] - A[0][1]*A[0][2]))
                 + logf(fabsf(A[1][0]*A[1][3] - A[1][1]*A[1][2]));
        out[NPIX + b] = ld * 196608.0f;        // p*(p/2)*C = 64*32*96
    }

    const int idx = blk * 256 + tid;
    const int wq = idx & 31;
    const int i  = (idx >> 5) & 63;
    const size_t base = ((size_t)r * 128 + i) * 128 + wq * 4;
    f32x4 top = *(const f32x4*)(x + base);
    f32x4 bot = *(const f32x4*)(x + base + 8192);
    const int wp = wq >> 4;
    const float a00 = A[wp][0], a01 = A[wp][1], a10 = A[wp][2], a11 = A[wp][3];
    f32x4 ot, ob;
    #pragma unroll
    for (int e = 0; e < 4; ++e){
        const bool mix = ((wp + e) & 1) != 0;
        ot[e] = mix ? (a00 * top[e] + a01 * bot[e]) : top[e];
        ob[e] = mix ? (a10 * top[e] + a11 * bot[e]) : bot[e];
    }
    __builtin_nontemporal_store(ot, (f32x4*)(out + base));
    __builtin_nontemporal_store(ob, (f32x4*)(out + base + 8192));
}

extern "C" void kernel_launch(void* const* d_in, const int* in_sizes, int n_in,
                              void* d_out, int out_size, void* d_ws, size_t ws_size,
                              hipStream_t stream){
    const float* x  = (const float*)d_in[0];
    const float* cq = (const float*)d_in[1];
    const float* ck = (const float*)d_in[2];
    const float* o1 = (const float*)d_in[3];
    const float* o2 = (const float*)d_in[4];
    const float* o3 = (const float*)d_in[5];
    float* out = (float*)d_out;
    float* ws  = (float*)d_ws;

    kG  <<<36, 256, 0, stream>>>(cq, ck, ws + WS_G);
    kM  <<<512, 384, 0, stream>>>(x, ws + WS_G, ws + WS_SP);
    kOut<<<24576, 256, 0, stream>>>(x, ws + WS_SP, o1, o2, o3, out);
}